// Round 19
// baseline (143.558 us; speedup 1.0000x reference)
//
#include <hip/hip_runtime.h>
#include <math.h>

#define N_NODES 100000
#define N_EDGES 3200000
#define IN_DIM  128
#define OUT_DIM 64

#define BSHIFT   7
#define BNODES   128                                   // nodes per bucket
#define NBUCKETS ((N_NODES + BNODES - 1) / BNODES)     // 782
#define NBINBLK  1024
#define CHUNK    (N_EDGES / NBINBLK)                   // 3125 (exact)
#define SEGCAP   6144                                  // max edges/bucket (mean 4096, +32 sigma)
#define MTILES   (N_NODES / 16)                        // 6250 (exact)
#define GEMM_BLOCKS ((MTILES + 3) / 4)                 // 1563
#define RSTAGE   (SEGCAP / 512)                        // 12 regs/thread

typedef _Float16 half8 __attribute__((ext_vector_type(8)));
typedef float    f32x4 __attribute__((ext_vector_type(4)));

// XCD-aware swizzle (verified round 11): 128 consecutive logical blocks per
// XCD -> bucket-major ebuf segments write-combine in one L2.
__device__ __forceinline__ int xcd_swz(int i) {
    return (i & 7) * (NBINBLK / 8) + (i >> 3);   // bijective: 1024 = 8*128
}

// Exclusive scan of Btot[0..NBUCKETS) into LDS bs[] (512 threads).
// Integer Hillis-Steele -- bit-identical offsets (verified round 17).
__device__ __forceinline__ void scan_btot(
    const int* __restrict__ Btot, int* bs, int* tmp)
{
    int t = threadIdx.x;
    const int C = (NBUCKETS + 511) / 512;   // 2
    int b0 = t * C;
    int s = 0;
#pragma unroll
    for (int i = 0; i < C; ++i) {
        int idx = b0 + i;
        int v = (idx < NBUCKETS) ? Btot[idx] : 0;
        if (idx < NBUCKETS) bs[idx] = v;
        s += v;
    }
    tmp[t] = s;
    __syncthreads();
#pragma unroll
    for (int o = 1; o < 512; o <<= 1) {
        int v = (t >= o) ? tmp[t - o] : 0;
        __syncthreads();
        tmp[t] += v;
        __syncthreads();
    }
    int excl = (t == 0) ? 0 : tmp[t - 1];
#pragma unroll
    for (int i = 0; i < C; ++i) {
        int idx = b0 + i;
        if (idx < NBUCKETS) { int v = bs[idx]; bs[idx] = excl; excl += v; }
    }
    __syncthreads();
}

// ---------------------------------------------------------------------------
// Fused kernel: blocks [0,NBINBLK) run bin_hist; blocks [NBINBLK, +GEMM)
// run the MFMA gemm.  (verified round 15)
// ---------------------------------------------------------------------------
__global__ __launch_bounds__(256) void fused_gemm_hist(
    const float* __restrict__ feature,
    const float* __restrict__ Wlin,     // [128][64] row-major fp32
    float* __restrict__ base,
    _Float16* __restrict__ u1h,
    const int* __restrict__ dst,
    int* __restrict__ H)
{
    __shared__ int h[NBUCKETS];

    if (blockIdx.x < NBINBLK) {
        // ---- bin_hist path (verified round 12) ----
        for (int k = threadIdx.x; k < NBUCKETS; k += 256) h[k] = 0;
        __syncthreads();

        int b = xcd_swz(blockIdx.x);
        int beg = b * CHUNK, end = beg + CHUNK;
        for (int i = beg + threadIdx.x; i < end; i += 256)
            atomicAdd(&h[dst[i] >> BSHIFT], 1);
        __syncthreads();

        for (int k = threadIdx.x; k < NBUCKETS; k += 256)
            H[(size_t)k * NBINBLK + b] = h[k];
        return;
    }

    // ---- gemm path (verified rounds 9-12) ----
    int lane = threadIdx.x & 63;
    int wid  = ((blockIdx.x - NBINBLK) * 256 + threadIdx.x) >> 6;
    if (wid >= MTILES) return;

    int mrow = lane & 15;       // A row / B col / C col
    int kb   = lane >> 4;       // k-block 0..3
    int k0   = kb * 8;

    half8 b[4][4];
#pragma unroll
    for (int s = 0; s < 4; ++s)
#pragma unroll
        for (int n = 0; n < 4; ++n)
#pragma unroll
            for (int j = 0; j < 8; ++j)
                b[s][n][j] = (_Float16)Wlin[(s * 32 + k0 + j) * OUT_DIM + n * 16 + mrow];

    int row = wid * 16 + mrow;
    const float4* fr = reinterpret_cast<const float4*>(feature + (size_t)row * IN_DIM);
    half8 a[4];
#pragma unroll
    for (int s = 0; s < 4; ++s) {
        float4 lo = fr[(s * 32 + k0) >> 2];
        float4 hi = fr[((s * 32 + k0) >> 2) + 1];
        a[s][0] = (_Float16)lo.x; a[s][1] = (_Float16)lo.y;
        a[s][2] = (_Float16)lo.z; a[s][3] = (_Float16)lo.w;
        a[s][4] = (_Float16)hi.x; a[s][5] = (_Float16)hi.y;
        a[s][6] = (_Float16)hi.z; a[s][7] = (_Float16)hi.w;
    }

    f32x4 acc[4];
#pragma unroll
    for (int n = 0; n < 4; ++n) acc[n] = (f32x4)0.f;

#pragma unroll
    for (int s = 0; s < 4; ++s)
#pragma unroll
        for (int n = 0; n < 4; ++n)
            acc[n] = __builtin_amdgcn_mfma_f32_16x16x32_f16(a[s], b[s][n], acc[n], 0, 0, 0);

#pragma unroll
    for (int n = 0; n < 4; ++n)
#pragma unroll
        for (int j = 0; j < 4; ++j) {
            int r = wid * 16 + kb * 4 + j;
            int c = n * 16 + mrow;
            float v = acc[n][j];
            base[(size_t)r * OUT_DIM + c] = v;
            u1h[(size_t)r * OUT_DIM + c] = (_Float16)tanhf(v);
        }
}

// ---------------------------------------------------------------------------
// scan_local: per-bucket exclusive scan of H row; Btot[k] = inclusive total.
// (verified round 12)
// ---------------------------------------------------------------------------
__global__ __launch_bounds__(NBINBLK) void scan_local(
    int* __restrict__ H, int* __restrict__ Btot)
{
    __shared__ int s[NBINBLK];
    int k = blockIdx.x, t = threadIdx.x;
    int v = H[(size_t)k * NBINBLK + t];
    s[t] = v;
    __syncthreads();
#pragma unroll
    for (int off = 1; off < NBINBLK; off <<= 1) {
        int x = (t >= off) ? s[t - off] : 0;
        __syncthreads();
        s[t] += x;
        __syncthreads();
    }
    H[(size_t)k * NBINBLK + t] = s[t] - v;      // exclusive (local, no base)
    if (t == NBINBLK - 1) Btot[k] = s[t];       // inclusive total
}

// ---------------------------------------------------------------------------
// bin_scatter: derives bucket bases from raw Btot in-prologue.
// (verified rounds 16-17)
// ---------------------------------------------------------------------------
__global__ __launch_bounds__(512) void bin_scatter(
    const int* __restrict__ src,
    const int* __restrict__ dst,
    const int* __restrict__ H,
    const int* __restrict__ Btot,
    int* __restrict__ ebuf)
{
    __shared__ int cur[NBUCKETS];
    __shared__ int bs[NBUCKETS];
    __shared__ int tmp[512];

    scan_btot(Btot, bs, tmp);

    int b = xcd_swz(blockIdx.x);
    for (int k = threadIdx.x; k < NBUCKETS; k += 512)
        cur[k] = H[(size_t)k * NBINBLK + b] + bs[k];
    __syncthreads();

    int beg = b * CHUNK, end = beg + CHUNK;
    for (int i = beg + threadIdx.x; i < end; i += 512) {
        int d = dst[i];
        int k = d >> BSHIFT;
        int p = atomicAdd(&cur[k], 1);
        // pack: src (17 bits) | dlocal (7 bits) << 17
        ebuf[p] = src[i] | ((d & (BNODES - 1)) << 17);
    }
}

// ---------------------------------------------------------------------------
// sort_gather_dense (round 19): fuses bucket_sort + node_gather + dense MLP.
//  1-3. identical to round-18 sort_gather, except m rows go to an LDS tile
//       m_tile[128][72] fp16 (same fp16 casts as the old mh buffer ->
//       bit-identical MFMA inputs) instead of global mh.
//  4.   barrier; the 8 waves run the verified dense MFMA recipe (wave w ->
//       rows w*16..w*16+15; transpose tile aliased onto seg, dead after
//       gather); out = tanh(base + relu(m@W1)@W2).
//  Saves: mh write+read (25.6 MB), the dense_tanh dispatch, node_off/csr.
// ---------------------------------------------------------------------------
__global__ __launch_bounds__(512) void sort_gather_dense(
    const int* __restrict__ Btot,
    const int* __restrict__ ebuf,
    const half8* __restrict__ u1v,      // [N_NODES][8] fp16
    const float* __restrict__ W1,       // [64][64]
    const float* __restrict__ W2,       // [64][64]
    const float* __restrict__ base,
    float* __restrict__ out)
{
    __shared__ int seg[SEGCAP];              // 24.6 KB; reused as tl in phase 4
    __shared__ _Float16 m_tile[128 * 72];    // 18.4 KB, row-padded (bank spread)
    __shared__ int cnt[BNODES];
    __shared__ int off[BNODES];
    __shared__ int st[BNODES + 1];
    __shared__ int bs[NBUCKETS];
    __shared__ int tmp[512];

    scan_btot(Btot, bs, tmp);

    int k = blockIdx.x;
    int beg = bs[k];
    int end = (k + 1 < NBUCKETS) ? bs[k + 1] : N_EDGES;
    int n = end - beg;
    int node0 = k * BNODES;

    for (int j = threadIdx.x; j < BNODES; j += 512) cnt[j] = 0;
    __syncthreads();

    // 1. stage to registers + histogram (static r[] indexing -- rule #20)
    int r[RSTAGE];
#pragma unroll
    for (int it = 0; it < RSTAGE; ++it) {
        int i = threadIdx.x + it * 512;
        int v = (i < n) ? ebuf[beg + i] : -1;
        r[it] = v;
        if (v >= 0) atomicAdd(&cnt[v >> 17], 1);
    }
    __syncthreads();

    // 2. per-node offsets within bucket
    if (threadIdx.x == 0) {
        int excl = 0;
        for (int j = 0; j < BNODES; ++j) {
            st[j] = excl; off[j] = excl; excl += cnt[j];
        }
        st[BNODES] = excl;              // == n
    }
    __syncthreads();

    // counting-sort scatter regs -> LDS seg
#pragma unroll
    for (int it = 0; it < RSTAGE; ++it) {
        int v = r[it];
        if (v >= 0) {
            int p = atomicAdd(&off[v >> 17], 1);
            seg[p] = v & 0x1FFFF;
        }
    }
    __syncthreads();

    // 3. gather: group g (8 lanes) handles local nodes g, g+64; m row ->
    //    LDS m_tile (fp16, identical cast to the old mh path)
    {
        int g = threadIdx.x >> 3;           // 0..63
        int c = threadIdx.x & 7;            // half8 column chunk

#pragma unroll
        for (int half = 0; half < 2; ++half) {
            int j = g + half * 64;
            int node = node0 + j;
            if (node >= N_NODES) break;
            int eb = st[j], ee = st[j + 1];

            float acc[8];
#pragma unroll
            for (int i = 0; i < 8; ++i) acc[i] = 0.f;

            int e = eb;
            for (; e + 4 <= ee; e += 4) {
                int s0 = seg[e];            // LDS broadcast across the 8 lanes
                int s1 = seg[e + 1];
                int s2 = seg[e + 2];
                int s3 = seg[e + 3];
                half8 a = u1v[(size_t)s0 * 8 + c];
                half8 b = u1v[(size_t)s1 * 8 + c];
                half8 gg = u1v[(size_t)s2 * 8 + c];
                half8 d = u1v[(size_t)s3 * 8 + c];
#pragma unroll
                for (int i = 0; i < 8; ++i)
                    acc[i] += ((float)a[i] + (float)b[i]) + ((float)gg[i] + (float)d[i]);
            }
            for (; e < ee; ++e) {
                half8 a = u1v[(size_t)seg[e] * 8 + c];
#pragma unroll
                for (int i = 0; i < 8; ++i) acc[i] += (float)a[i];
            }

            half8 hv;
#pragma unroll
            for (int i = 0; i < 8; ++i) hv[i] = (_Float16)acc[i];
            *reinterpret_cast<half8*>(&m_tile[j * 72 + c * 8]) = hv;
        }
    }
    __syncthreads();    // all seg reads + m_tile writes complete

    // 4. dense layers (verified round-12 recipe).  Wave w: rows w*16..+15.
    //    tl transpose tile aliased onto seg (dead now).
    {
        int lane = threadIdx.x & 63;
        int w    = threadIdx.x >> 6;        // 0..7
        int mrow = lane & 15;
        int kb   = lane >> 4;
        int k0   = kb * 8;
        _Float16* tlw = reinterpret_cast<_Float16*>(seg) + w * 16 * 72;

        half8 b1[2][4], b2[2][4];
#pragma unroll
        for (int s = 0; s < 2; ++s)
#pragma unroll
            for (int nn = 0; nn < 4; ++nn)
#pragma unroll
                for (int j = 0; j < 8; ++j) {
                    b1[s][nn][j] = (_Float16)W1[(s * 32 + k0 + j) * 64 + nn * 16 + mrow];
                    b2[s][nn][j] = (_Float16)W2[(s * 32 + k0 + j) * 64 + nn * 16 + mrow];
                }

        // A-frags from the LDS m tile (bit-identical to old mh loads)
        half8 a[2];
#pragma unroll
        for (int s = 0; s < 2; ++s)
            a[s] = *reinterpret_cast<const half8*>(
                &m_tile[(w * 16 + mrow) * 72 + s * 32 + k0]);

        f32x4 acc1[4];
#pragma unroll
        for (int nn = 0; nn < 4; ++nn) acc1[nn] = (f32x4)0.f;
#pragma unroll
        for (int s = 0; s < 2; ++s)
#pragma unroll
            for (int nn = 0; nn < 4; ++nn)
                acc1[nn] = __builtin_amdgcn_mfma_f32_16x16x32_f16(a[s], b1[s][nn], acc1[nn], 0, 0, 0);

#pragma unroll
        for (int nn = 0; nn < 4; ++nn)
#pragma unroll
            for (int j = 0; j < 4; ++j)
                tlw[(kb * 4 + j) * 72 + nn * 16 + mrow] = (_Float16)fmaxf(acc1[nn][j], 0.f);

        half8 a2[2];
#pragma unroll
        for (int s = 0; s < 2; ++s)
            a2[s] = *reinterpret_cast<const half8*>(&tlw[mrow * 72 + s * 32 + k0]);

        f32x4 acc2[4];
#pragma unroll
        for (int nn = 0; nn < 4; ++nn) acc2[nn] = (f32x4)0.f;
#pragma unroll
        for (int s = 0; s < 2; ++s)
#pragma unroll
            for (int nn = 0; nn < 4; ++nn)
                acc2[nn] = __builtin_amdgcn_mfma_f32_16x16x32_f16(a2[s], b2[s][nn], acc2[nn], 0, 0, 0);

#pragma unroll
        for (int nn = 0; nn < 4; ++nn)
#pragma unroll
            for (int j = 0; j < 4; ++j) {
                int rr = node0 + w * 16 + kb * 4 + j;
                if (rr < N_NODES) {
                    int c = nn * 16 + mrow;
                    out[(size_t)rr * 64 + c] =
                        tanhf(base[(size_t)rr * 64 + c] + acc2[nn][j]);
                }
            }
    }
}

// ---------------------------------------------------------------------------
extern "C" void kernel_launch(void* const* d_in, const int* in_sizes, int n_in,
                              void* d_out, int out_size, void* d_ws, size_t ws_size,
                              hipStream_t stream)
{
    const float* feature = (const float*)d_in[0];
    const int*   src     = (const int*)d_in[1];
    const int*   dst     = (const int*)d_in[2];
    const float* W_lin   = (const float*)d_in[3];
    const float* W_d1    = (const float*)d_in[4];
    const float* W_d2    = (const float*)d_in[5];
    float* out = (float*)d_out;

    const size_t NODE_F = (size_t)N_NODES * OUT_DIM;   // 6.4M elems

    float*    base     = (float*)d_ws;                          // 25.6 MB
    _Float16* u1h      = (_Float16*)(base + NODE_F);            // 12.8 MB
    int*      H        = (int*)(u1h + NODE_F);                  // 3.2 MB
    int*      Btot     = H + ((size_t)NBUCKETS * NBINBLK + 4);  // NBUCKETS
    int*      ebuf     = Btot + (NBUCKETS + 4);                 // 3.2M ints

    // iter 1 collapses: u0 == 0 -> m == 0 -> h == 0 -> u1 = tanh(feature@W_lin)
    fused_gemm_hist<<<NBINBLK + GEMM_BLOCKS, 256, 0, stream>>>(
        feature, W_lin, base, u1h, dst, H);

    scan_local<<<NBUCKETS, NBINBLK, 0, stream>>>(H, Btot);
    bin_scatter<<<NBINBLK, 512, 0, stream>>>(src, dst, H, Btot, ebuf);
    sort_gather_dense<<<NBUCKETS, 512, 0, stream>>>(
        Btot, ebuf, (const half8*)u1h, W_d1, W_d2, base, out);
}

// Round 20
// 139.859 us; speedup vs baseline: 1.0264x; 1.0264x over previous
//
#include <hip/hip_runtime.h>
#include <math.h>

#define N_NODES 100000
#define N_EDGES 3200000
#define IN_DIM  128
#define OUT_DIM 64

#define BSHIFT   7
#define BNODES   128                                   // nodes per bucket
#define NBUCKETS ((N_NODES + BNODES - 1) / BNODES)     // 782
#define NBINBLK  1024
#define CHUNK    (N_EDGES / NBINBLK)                   // 3125 (exact)
#define SEGCAP   6144                                  // max edges/bucket (mean 4096, +32 sigma)
#define MTILES   (N_NODES / 16)                        // 6250 (exact)
#define GEMM_BLOCKS ((MTILES + 3) / 4)                 // 1563
#define RSTAGE   (SEGCAP / 512)                        // 12 regs/thread

typedef _Float16 half8 __attribute__((ext_vector_type(8)));
typedef float    f32x4 __attribute__((ext_vector_type(4)));

// XCD-aware swizzle (verified round 11): 128 consecutive logical blocks per
// XCD -> bucket-major ebuf segments write-combine in one L2.
__device__ __forceinline__ int xcd_swz(int i) {
    return (i & 7) * (NBINBLK / 8) + (i >> 3);   // bijective: 1024 = 8*128
}

// Exclusive scan of Btot[0..NBUCKETS) into LDS bs[] (512 threads).
// Integer Hillis-Steele -- bit-identical offsets (verified round 17).
__device__ __forceinline__ void scan_btot(
    const int* __restrict__ Btot, int* bs, int* tmp)
{
    int t = threadIdx.x;
    const int C = (NBUCKETS + 511) / 512;   // 2
    int b0 = t * C;
    int s = 0;
#pragma unroll
    for (int i = 0; i < C; ++i) {
        int idx = b0 + i;
        int v = (idx < NBUCKETS) ? Btot[idx] : 0;
        if (idx < NBUCKETS) bs[idx] = v;
        s += v;
    }
    tmp[t] = s;
    __syncthreads();
#pragma unroll
    for (int o = 1; o < 512; o <<= 1) {
        int v = (t >= o) ? tmp[t - o] : 0;
        __syncthreads();
        tmp[t] += v;
        __syncthreads();
    }
    int excl = (t == 0) ? 0 : tmp[t - 1];
#pragma unroll
    for (int i = 0; i < C; ++i) {
        int idx = b0 + i;
        if (idx < NBUCKETS) { int v = bs[idx]; bs[idx] = excl; excl += v; }
    }
    __syncthreads();
}

// ---------------------------------------------------------------------------
// Fused kernel: blocks [0,NBINBLK) run bin_hist; blocks [NBINBLK, +GEMM)
// run the MFMA gemm.  (verified round 15; base narrowed to fp16 round 20)
// ---------------------------------------------------------------------------
__global__ __launch_bounds__(256) void fused_gemm_hist(
    const float* __restrict__ feature,
    const float* __restrict__ Wlin,     // [128][64] row-major fp32
    _Float16* __restrict__ baseh,
    _Float16* __restrict__ u1h,
    const int* __restrict__ dst,
    int* __restrict__ H)
{
    __shared__ int h[NBUCKETS];

    if (blockIdx.x < NBINBLK) {
        // ---- bin_hist path (verified round 12) ----
        for (int k = threadIdx.x; k < NBUCKETS; k += 256) h[k] = 0;
        __syncthreads();

        int b = xcd_swz(blockIdx.x);
        int beg = b * CHUNK, end = beg + CHUNK;
        for (int i = beg + threadIdx.x; i < end; i += 256)
            atomicAdd(&h[dst[i] >> BSHIFT], 1);
        __syncthreads();

        for (int k = threadIdx.x; k < NBUCKETS; k += 256)
            H[(size_t)k * NBINBLK + b] = h[k];
        return;
    }

    // ---- gemm path (verified rounds 9-12) ----
    int lane = threadIdx.x & 63;
    int wid  = ((blockIdx.x - NBINBLK) * 256 + threadIdx.x) >> 6;
    if (wid >= MTILES) return;

    int mrow = lane & 15;       // A row / B col / C col
    int kb   = lane >> 4;       // k-block 0..3
    int k0   = kb * 8;

    half8 b[4][4];
#pragma unroll
    for (int s = 0; s < 4; ++s)
#pragma unroll
        for (int n = 0; n < 4; ++n)
#pragma unroll
            for (int j = 0; j < 8; ++j)
                b[s][n][j] = (_Float16)Wlin[(s * 32 + k0 + j) * OUT_DIM + n * 16 + mrow];

    int row = wid * 16 + mrow;
    const float4* fr = reinterpret_cast<const float4*>(feature + (size_t)row * IN_DIM);
    half8 a[4];
#pragma unroll
    for (int s = 0; s < 4; ++s) {
        float4 lo = fr[(s * 32 + k0) >> 2];
        float4 hi = fr[((s * 32 + k0) >> 2) + 1];
        a[s][0] = (_Float16)lo.x; a[s][1] = (_Float16)lo.y;
        a[s][2] = (_Float16)lo.z; a[s][3] = (_Float16)lo.w;
        a[s][4] = (_Float16)hi.x; a[s][5] = (_Float16)hi.y;
        a[s][6] = (_Float16)hi.z; a[s][7] = (_Float16)hi.w;
    }

    f32x4 acc[4];
#pragma unroll
    for (int n = 0; n < 4; ++n) acc[n] = (f32x4)0.f;

#pragma unroll
    for (int s = 0; s < 4; ++s)
#pragma unroll
        for (int n = 0; n < 4; ++n)
            acc[n] = __builtin_amdgcn_mfma_f32_16x16x32_f16(a[s], b[s][n], acc[n], 0, 0, 0);

#pragma unroll
    for (int n = 0; n < 4; ++n)
#pragma unroll
        for (int j = 0; j < 4; ++j) {
            int r = wid * 16 + kb * 4 + j;
            int c = n * 16 + mrow;
            float v = acc[n][j];
            baseh[(size_t)r * OUT_DIM + c] = (_Float16)v;
            u1h[(size_t)r * OUT_DIM + c]  = (_Float16)tanhf(v);
        }
}

// ---------------------------------------------------------------------------
// scan_local: per-bucket exclusive scan of H row; Btot[k] = inclusive total.
// (verified round 12)
// ---------------------------------------------------------------------------
__global__ __launch_bounds__(NBINBLK) void scan_local(
    int* __restrict__ H, int* __restrict__ Btot)
{
    __shared__ int s[NBINBLK];
    int k = blockIdx.x, t = threadIdx.x;
    int v = H[(size_t)k * NBINBLK + t];
    s[t] = v;
    __syncthreads();
#pragma unroll
    for (int off = 1; off < NBINBLK; off <<= 1) {
        int x = (t >= off) ? s[t - off] : 0;
        __syncthreads();
        s[t] += x;
        __syncthreads();
    }
    H[(size_t)k * NBINBLK + t] = s[t] - v;      // exclusive (local, no base)
    if (t == NBINBLK - 1) Btot[k] = s[t];       // inclusive total
}

// ---------------------------------------------------------------------------
// bin_scatter: derives bucket bases from raw Btot in-prologue.
// (verified rounds 16-17)
// ---------------------------------------------------------------------------
__global__ __launch_bounds__(512) void bin_scatter(
    const int* __restrict__ src,
    const int* __restrict__ dst,
    const int* __restrict__ H,
    const int* __restrict__ Btot,
    int* __restrict__ ebuf)
{
    __shared__ int cur[NBUCKETS];
    __shared__ int bs[NBUCKETS];
    __shared__ int tmp[512];

    scan_btot(Btot, bs, tmp);

    int b = xcd_swz(blockIdx.x);
    for (int k = threadIdx.x; k < NBUCKETS; k += 512)
        cur[k] = H[(size_t)k * NBINBLK + b] + bs[k];
    __syncthreads();

    int beg = b * CHUNK, end = beg + CHUNK;
    for (int i = beg + threadIdx.x; i < end; i += 512) {
        int d = dst[i];
        int k = d >> BSHIFT;
        int p = atomicAdd(&cur[k], 1);
        // pack: src (17 bits) | dlocal (7 bits) << 17
        ebuf[p] = src[i] | ((d & (BNODES - 1)) << 17);
    }
}

// ---------------------------------------------------------------------------
// sort_gather: fuses bucket_sort + node_gather.  (verified round 18)
// ---------------------------------------------------------------------------
__global__ __launch_bounds__(512) void sort_gather(
    const int* __restrict__ Btot,
    const int* __restrict__ ebuf,
    const half8* __restrict__ u1v,      // [N_NODES][8] fp16
    half8* __restrict__ mh)             // [N_NODES][8] fp16
{
    __shared__ int seg[SEGCAP];
    __shared__ int cnt[BNODES];
    __shared__ int off[BNODES];
    __shared__ int st[BNODES + 1];
    __shared__ int bs[NBUCKETS];
    __shared__ int tmp[512];

    scan_btot(Btot, bs, tmp);

    int k = blockIdx.x;
    int beg = bs[k];
    int end = (k + 1 < NBUCKETS) ? bs[k + 1] : N_EDGES;
    int n = end - beg;

    for (int j = threadIdx.x; j < BNODES; j += 512) cnt[j] = 0;
    __syncthreads();

    // 1. stage to registers + histogram (static r[] indexing -- rule #20)
    int r[RSTAGE];
#pragma unroll
    for (int it = 0; it < RSTAGE; ++it) {
        int i = threadIdx.x + it * 512;
        int v = (i < n) ? ebuf[beg + i] : -1;
        r[it] = v;
        if (v >= 0) atomicAdd(&cnt[v >> 17], 1);
    }
    __syncthreads();

    // 2. per-node offsets within bucket
    if (threadIdx.x == 0) {
        int excl = 0;
        for (int j = 0; j < BNODES; ++j) {
            st[j] = excl; off[j] = excl; excl += cnt[j];
        }
        st[BNODES] = excl;              // == n
    }
    __syncthreads();

    // counting-sort scatter regs -> LDS seg
#pragma unroll
    for (int it = 0; it < RSTAGE; ++it) {
        int v = r[it];
        if (v >= 0) {
            int p = atomicAdd(&off[v >> 17], 1);
            seg[p] = v & 0x1FFFF;
        }
    }
    __syncthreads();

    // 3. gather: group g (8 lanes) handles local nodes g, g+64
    int g = threadIdx.x >> 3;           // 0..63
    int c = threadIdx.x & 7;            // half8 column chunk
    int node0 = k * BNODES;

#pragma unroll
    for (int half = 0; half < 2; ++half) {
        int j = g + half * 64;
        int node = node0 + j;
        if (node >= N_NODES) break;
        int eb = st[j], ee = st[j + 1];

        float acc[8];
#pragma unroll
        for (int i = 0; i < 8; ++i) acc[i] = 0.f;

        int e = eb;
        for (; e + 4 <= ee; e += 4) {
            int s0 = seg[e];            // LDS broadcast across the 8 lanes
            int s1 = seg[e + 1];
            int s2 = seg[e + 2];
            int s3 = seg[e + 3];
            half8 a = u1v[(size_t)s0 * 8 + c];
            half8 b = u1v[(size_t)s1 * 8 + c];
            half8 gg = u1v[(size_t)s2 * 8 + c];
            half8 d = u1v[(size_t)s3 * 8 + c];
#pragma unroll
            for (int i = 0; i < 8; ++i)
                acc[i] += ((float)a[i] + (float)b[i]) + ((float)gg[i] + (float)d[i]);
        }
        for (; e < ee; ++e) {
            half8 a = u1v[(size_t)seg[e] * 8 + c];
#pragma unroll
            for (int i = 0; i < 8; ++i) acc[i] += (float)a[i];
        }

        half8 hv;
#pragma unroll
        for (int i = 0; i < 8; ++i) hv[i] = (_Float16)acc[i];
        mh[(size_t)node * 8 + c] = hv;  // 8 lanes x 16 B = 128 B row
    }
}

// ---------------------------------------------------------------------------
// Kernel 3 (MFMA): out = tanh(base + relu(m @ W_d1) @ W_d2)
// (verified rounds 12/17; base read as fp16 round 20)
// ---------------------------------------------------------------------------
__global__ __launch_bounds__(256) void dense_tanh(
    const half8* __restrict__ mh,       // [N_NODES][8] fp16
    const float* __restrict__ W1,       // [64][64]
    const float* __restrict__ W2,       // [64][64]
    const _Float16* __restrict__ baseh,
    float* __restrict__ out)
{
    __shared__ _Float16 tl[4][16][72];  // 9 KB: per-wave transpose tile
    int lane = threadIdx.x & 63;
    int w    = threadIdx.x >> 6;        // wave in block
    int wid  = (blockIdx.x * 256 + threadIdx.x) >> 6;
    if (wid >= MTILES) return;

    int mrow = lane & 15;
    int kb   = lane >> 4;
    int k0   = kb * 8;

    half8 b1[2][4], b2[2][4];
#pragma unroll
    for (int s = 0; s < 2; ++s)
#pragma unroll
        for (int n = 0; n < 4; ++n)
#pragma unroll
            for (int j = 0; j < 8; ++j) {
                b1[s][n][j] = (_Float16)W1[(s * 32 + k0 + j) * 64 + n * 16 + mrow];
                b2[s][n][j] = (_Float16)W2[(s * 32 + k0 + j) * 64 + n * 16 + mrow];
            }

    int row = wid * 16 + mrow;
    half8 a[2];
#pragma unroll
    for (int s = 0; s < 2; ++s)
        a[s] = mh[(size_t)row * 8 + ((s * 32 + k0) >> 3)];

    f32x4 acc1[4];
#pragma unroll
    for (int n = 0; n < 4; ++n) acc1[n] = (f32x4)0.f;
#pragma unroll
    for (int s = 0; s < 2; ++s)
#pragma unroll
        for (int n = 0; n < 4; ++n)
            acc1[n] = __builtin_amdgcn_mfma_f32_16x16x32_f16(a[s], b1[s][n], acc1[n], 0, 0, 0);

#pragma unroll
    for (int n = 0; n < 4; ++n)
#pragma unroll
        for (int j = 0; j < 4; ++j)
            tl[w][kb * 4 + j][n * 16 + mrow] = (_Float16)fmaxf(acc1[n][j], 0.f);

    half8 a2[2];
#pragma unroll
    for (int s = 0; s < 2; ++s)
        a2[s] = *reinterpret_cast<const half8*>(&tl[w][mrow][s * 32 + k0]);

    f32x4 acc2[4];
#pragma unroll
    for (int n = 0; n < 4; ++n) acc2[n] = (f32x4)0.f;
#pragma unroll
    for (int s = 0; s < 2; ++s)
#pragma unroll
        for (int n = 0; n < 4; ++n)
            acc2[n] = __builtin_amdgcn_mfma_f32_16x16x32_f16(a2[s], b2[s][n], acc2[n], 0, 0, 0);

#pragma unroll
    for (int n = 0; n < 4; ++n)
#pragma unroll
        for (int j = 0; j < 4; ++j) {
            int r = wid * 16 + kb * 4 + j;
            int c = n * 16 + mrow;
            float b0 = (float)baseh[(size_t)r * 64 + c];
            out[(size_t)r * 64 + c] = tanhf(b0 + acc2[n][j]);
        }
}

// ---------------------------------------------------------------------------
extern "C" void kernel_launch(void* const* d_in, const int* in_sizes, int n_in,
                              void* d_out, int out_size, void* d_ws, size_t ws_size,
                              hipStream_t stream)
{
    const float* feature = (const float*)d_in[0];
    const int*   src     = (const int*)d_in[1];
    const int*   dst     = (const int*)d_in[2];
    const float* W_lin   = (const float*)d_in[3];
    const float* W_d1    = (const float*)d_in[4];
    const float* W_d2    = (const float*)d_in[5];
    float* out = (float*)d_out;

    const size_t NODE_F = (size_t)N_NODES * OUT_DIM;   // 6.4M elems

    _Float16* baseh    = (_Float16*)d_ws;                       // 12.8 MB
    _Float16* u1h      = baseh + NODE_F;                        // 12.8 MB
    _Float16* mh       = u1h + NODE_F;                          // 12.8 MB
    int*      H        = (int*)(mh + NODE_F);                   // 3.2 MB
    int*      Btot     = H + ((size_t)NBUCKETS * NBINBLK + 4);  // NBUCKETS
    int*      ebuf     = Btot + (NBUCKETS + 4);                 // 3.2M ints

    // iter 1 collapses: u0 == 0 -> m == 0 -> h == 0 -> u1 = tanh(feature@W_lin)
    fused_gemm_hist<<<NBINBLK + GEMM_BLOCKS, 256, 0, stream>>>(
        feature, W_lin, baseh, u1h, dst, H);

    scan_local<<<NBUCKETS, NBINBLK, 0, stream>>>(H, Btot);
    bin_scatter<<<NBINBLK, 512, 0, stream>>>(src, dst, H, Btot, ebuf);
    sort_gather<<<NBUCKETS, 512, 0, stream>>>(
        Btot, ebuf, (const half8*)u1h, (half8*)mh);

    dense_tanh<<<GEMM_BLOCKS, 256, 0, stream>>>(
        (const half8*)mh, W_d1, W_d2, baseh, out);
}